// Round 3
// baseline (256.455 us; speedup 1.0000x reference)
//
#include <hip/hip_runtime.h>
#include <math.h>

// MultiHeadModulator: single-query complex multi-head attention over L=65536
// past positions, dim=256 (d2=512 real), H=8 heads.
//
// Algebraic reduction (k_proj/v_proj never materialized):
//   scores[l,h] = sum_i z[l,i]*wk[h,i] + ck[h] + relq[idx(l),h]
//   S_un[h,i]   = sum_l exp(scores[l,h]) * z[l,i]     (no max-sub: scores ~N(0,0.5))
//   s[h]        = sum_l exp(scores[l,h])
//   out_real[j] = sum_i Wv[j,i]*S_un[h(j),i]/s[h(j)] + bv[j]
//   out[j']     = sum_j Wo[j',j]*out_real[j] + bo[j']
//
// v4: atomic combine (v2 direct: +17us, v3 slotted: +9us vs v1) is a dead end
// -- 2M device-scope RMWs run ~15x slower than streaming stores. Revert to
// v1's streaming Sp + k_comb2 (16-way atomic only). Keep the two v2 pieces
// that were masked by the atomic regression:
//   - k_wkpart+k_misc fused into k_front2 (7 -> 6 launches, identical work)
//   - depth-2 register prefetch in k_attn (16KB -> 32KB in flight per CU,
//     covers ~900cy HBM latency at 24.6 GB/s/CU; +8 VGPR, same occupancy)

static constexpr float SCALE = 0.17677669529663687f; // 1/sqrt(32)

__device__ __forceinline__ float wave_sum(float v) {
#pragma unroll
  for (int off = 32; off > 0; off >>= 1) v += __shfl_xor(v, off, 64);
  return v;
}

// y[j] = bias[j] + sum_i x[i]*M[j*512+i], 512 rows, one wave per row. grid=128
__global__ __launch_bounds__(256) void k_matvec512(
    const float* __restrict__ M, const float* __restrict__ x,
    const float* __restrict__ bias, float* __restrict__ y) {
  const int wave = threadIdx.x >> 6, lane = threadIdx.x & 63;
  const int j = blockIdx.x * 4 + wave;
  const float* Mr = M + (size_t)j * 512 + lane * 8;
  const float4 m0 = *(const float4*)Mr;
  const float4 m1 = *(const float4*)(Mr + 4);
  const float4 x0 = *(const float4*)(x + lane * 8);
  const float4 x1 = *(const float4*)(x + lane * 8 + 4);
  float acc = m0.x * x0.x + m0.y * x0.y + m0.z * x0.z + m0.w * x0.w +
              m1.x * x1.x + m1.y * x1.y + m1.z * x1.z + m1.w * x1.w;
  acc = wave_sum(acc);
  if (lane == 0) y[j] = acc + bias[j];
}

// Fused front-end stage 2 (needs qp). grid = 24:
//  blocks 0..15 : wk[h,i] = SCALE * sum_{k<64} qp[h*64+k]*Wk[(h*64+k)*512+i]
//                 (block b: h=b>>1, i=(b&1)*256+tid; single-stage)
//  blocks 16..21: relq[idx*8+h] = SCALE * sum_k qp[h*64+k]*rb[idx*512+h*64+k]
//  block 22     : ck[h] = SCALE * sum_k qp[h*64+k]*bk[h*64+k]
//  block 23     : zero S_un[4096]
__global__ __launch_bounds__(256) void k_front2(
    const float* __restrict__ Wk, const float* __restrict__ qp,
    const float* __restrict__ bk, const float* __restrict__ rb,
    float* __restrict__ wk, float* __restrict__ ck, float* __restrict__ relq,
    float* __restrict__ S_un) {
  __shared__ float ql[512];
  const int b = blockIdx.x;
  if (b < 16) {
    const int h = b >> 1;
    if (threadIdx.x < 64) ql[threadIdx.x] = qp[h * 64 + threadIdx.x];
    __syncthreads();
    const int i = (b & 1) * 256 + threadIdx.x;
    float acc = 0.f;
#pragma unroll
    for (int k = 0; k < 64; ++k)
      acc += ql[k] * Wk[(size_t)(h * 64 + k) * 512 + i];
    wk[h * 512 + i] = acc * SCALE;
  } else if (b < 22) {
    for (int t = threadIdx.x; t < 512; t += 256) ql[t] = qp[t];
    __syncthreads();
    const int t = (b - 16) * 256 + threadIdx.x;
    if (t < 129 * 8) {
      const int idx = t >> 3, h = t & 7;
      float acc = 0.f;
#pragma unroll
      for (int k = 0; k < 64; ++k)
        acc += ql[h * 64 + k] * rb[(size_t)idx * 512 + h * 64 + k];
      relq[t] = acc * SCALE;
    }
  } else if (b == 22) {
    if (threadIdx.x < 8) {
      const int h = threadIdx.x;
      float acc = 0.f;
      for (int k = 0; k < 64; ++k) acc += qp[h * 64 + k] * bk[h * 64 + k];
      ck[h] = acc * SCALE;
    }
  } else {
    for (int t = threadIdx.x; t < 4096; t += 256) S_un[t] = 0.f;
  }
}

// Fused single pass: scores + exp + weighted z accumulation.
// 128 rows/block (32/wave), grid = L/128 = 512 -> 2 blocks/CU.
// Streaming-store tail: block partial tiles to Sp/sp (combined by k_comb2).
__global__ __launch_bounds__(256, 2) void k_attn(
    const float* __restrict__ zp, const float* __restrict__ wk,
    const float* __restrict__ ck, const float* __restrict__ relq,
    const int* __restrict__ curr_pos, int L, float* __restrict__ Sp,
    float* __restrict__ sp) {
  __shared__ float relql[1032];
  __shared__ float Sl[4096];
  __shared__ float sl[4][8];
  const int tid = threadIdx.x;
  const int wave = tid >> 6, lane = tid & 63;
  for (int t = tid; t < 1032; t += 256) relql[t] = relq[t];

  float wkr[8][8];
#pragma unroll
  for (int h = 0; h < 8; ++h) {
    const float4 a = *(const float4*)(wk + h * 512 + lane * 8);
    const float4 b = *(const float4*)(wk + h * 512 + lane * 8 + 4);
    wkr[h][0] = a.x; wkr[h][1] = a.y; wkr[h][2] = a.z; wkr[h][3] = a.w;
    wkr[h][4] = b.x; wkr[h][5] = b.y; wkr[h][6] = b.z; wkr[h][7] = b.w;
  }
  // fold-reduce leaves lane holding head myh = bitrev3(lane&7)
  const int myh = ((lane & 1) << 2) | (lane & 2) | ((lane >> 2) & 1);
  const float ck_my = ck[myh];
  const int cp = curr_pos[0];
  __syncthreads();

  float S[8][8];
#pragma unroll
  for (int h = 0; h < 8; ++h)
#pragma unroll
    for (int k = 0; k < 8; ++k) S[h][k] = 0.f;
  float s_loc = 0.f;

  const int l0 = blockIdx.x * 128 + wave * 32;
  const float* zr = zp + (size_t)l0 * 512 + lane * 8;
  // depth-2 register prefetch: p = row r, q = row r+1, n = row r+2
  float4 p0 = *(const float4*)zr;
  float4 p1 = *(const float4*)(zr + 4);
  const float* z1p = (l0 + 1 < L) ? (zr + 512) : zr;
  float4 q0 = *(const float4*)z1p;
  float4 q1 = *(const float4*)(z1p + 4);

#pragma unroll 2
  for (int r = 0; r < 32; ++r) {
    const int l = l0 + r;
    const float* zn = (l + 2 < L) ? (zr + 1024) : zr;
    const float4 n0 = *(const float4*)zn;
    const float4 n1 = *(const float4*)(zn + 4);
    const float zz[8] = {p0.x, p0.y, p0.z, p0.w, p1.x, p1.y, p1.z, p1.w};
    float acc[8];
#pragma unroll
    for (int h = 0; h < 8; ++h) {
      float a = 0.f;
#pragma unroll
      for (int k = 0; k < 8; ++k) a += zz[k] * wkr[h][k];
      acc[h] = a;
    }
    // fold-reduce: 8 values across 64 lanes in 10 shuffles
    const bool lo1 = (lane & 1) == 0;
    float b0 = (lo1 ? acc[0] : acc[4]) + __shfl_xor(lo1 ? acc[4] : acc[0], 1, 64);
    float b1 = (lo1 ? acc[1] : acc[5]) + __shfl_xor(lo1 ? acc[5] : acc[1], 1, 64);
    float b2 = (lo1 ? acc[2] : acc[6]) + __shfl_xor(lo1 ? acc[6] : acc[2], 1, 64);
    float b3 = (lo1 ? acc[3] : acc[7]) + __shfl_xor(lo1 ? acc[7] : acc[3], 1, 64);
    const bool lo2 = (lane & 2) == 0;
    float c0 = (lo2 ? b0 : b2) + __shfl_xor(lo2 ? b2 : b0, 2, 64);
    float c1 = (lo2 ? b1 : b3) + __shfl_xor(lo2 ? b3 : b1, 2, 64);
    const bool lo3 = (lane & 4) == 0;
    float d = (lo3 ? c0 : c1) + __shfl_xor(lo3 ? c1 : c0, 4, 64);
    d += __shfl_xor(d, 8, 64);
    d += __shfl_xor(d, 16, 64);
    d += __shfl_xor(d, 32, 64);

    int dd = cp - L + l + 64;
    dd = dd < 0 ? 0 : (dd > 128 ? 128 : dd);
    float w = __expf(d + ck_my + relql[dd * 8 + myh]);
    if (l >= L) w = 0.f;
    s_loc += w;
#pragma unroll
    for (int h = 0; h < 8; ++h) {
      const int src = ((h & 1) << 2) | (h & 2) | ((h >> 2) & 1);
      const float wh = __shfl(w, src, 64);
#pragma unroll
      for (int k = 0; k < 8; ++k) S[h][k] += wh * zz[k];
    }
    p0 = q0; p1 = q1; q0 = n0; q1 = n1; zr += 512;
  }

  if (lane < 8) sl[wave][myh] = s_loc;
  // merge the 4 waves' register tiles into LDS
  for (int wv = 0; wv < 4; ++wv) {
    if (wave == wv) {
#pragma unroll
      for (int h = 0; h < 8; ++h)
#pragma unroll
        for (int k = 0; k < 8; ++k) {
          const int idx = h * 512 + lane * 8 + k;
          if (wv == 0) Sl[idx] = S[h][k];
          else Sl[idx] += S[h][k];
        }
    }
    __syncthreads();
  }
  for (int t = tid; t < 4096; t += 256)
    Sp[(size_t)blockIdx.x * 4096 + t] = Sl[t];
  if (tid < 8)
    sp[blockIdx.x * 8 + tid] = sl[0][tid] + sl[1][tid] + sl[2][tid] + sl[3][tid];
}

// combine block partials. blocks 0..255: S_un (atomic, pre-zeroed);
// block 256: s. grid=257
__global__ __launch_bounds__(256) void k_comb2(
    const float* __restrict__ Sp, const float* __restrict__ spv, int nb,
    float* __restrict__ S_un, float* __restrict__ s) {
  if (blockIdx.x < 256) {
    const int T = blockIdx.x * 256 + threadIdx.x;
    const int col = T & 4095;
    const int g = T >> 12;  // 0..15
    const int chunk = (nb + 15) >> 4;
    const int r0 = g * chunk;
    const int r1 = min(r0 + chunk, nb);
    float a[8];
#pragma unroll
    for (int u = 0; u < 8; ++u) a[u] = 0.f;
    int b = r0;
    for (; b + 8 <= r1; b += 8) {
#pragma unroll
      for (int u = 0; u < 8; ++u) a[u] += Sp[(size_t)(b + u) * 4096 + col];
    }
    for (; b < r1; ++b) a[0] += Sp[(size_t)b * 4096 + col];
    const float t = ((a[0] + a[1]) + (a[2] + a[3])) +
                    ((a[4] + a[5]) + (a[6] + a[7]));
    atomicAdd(&S_un[col], t);
  } else {
    __shared__ float red[256];
    float a = 0.f;
    for (int b2 = threadIdx.x >> 3; b2 < nb; b2 += 32)
      a += spv[b2 * 8 + (threadIdx.x & 7)];
    red[threadIdx.x] = a;
    __syncthreads();
    if (threadIdx.x < 8) {
      float x = 0.f;
      for (int c = 0; c < 32; ++c) x += red[c * 8 + threadIdx.x];
      s[threadIdx.x] = x;
    }
  }
}

// out_real[j] = bv[j] + (sum_i Wv[j,i]*S_un[h(j),i]) / s[h(j)]. grid=128
__global__ __launch_bounds__(256) void k_outreal(
    const float* __restrict__ Wv, const float* __restrict__ S_un,
    const float* __restrict__ s, const float* __restrict__ bv,
    float* __restrict__ out_real) {
  const int wave = threadIdx.x >> 6, lane = threadIdx.x & 63;
  const int j = blockIdx.x * 4 + wave;
  const int h = j >> 6;
  const float* Mr = Wv + (size_t)j * 512 + lane * 8;
  const float* xr = S_un + h * 512 + lane * 8;
  const float4 m0 = *(const float4*)Mr;
  const float4 m1 = *(const float4*)(Mr + 4);
  const float4 x0 = *(const float4*)xr;
  const float4 x1 = *(const float4*)(xr + 4);
  float acc = m0.x * x0.x + m0.y * x0.y + m0.z * x0.z + m0.w * x0.w +
              m1.x * x1.x + m1.y * x1.y + m1.z * x1.z + m1.w * x1.w;
  acc = wave_sum(acc);
  if (lane == 0) out_real[j] = acc / s[h] + bv[j];
}

extern "C" void kernel_launch(void* const* d_in, const int* in_sizes, int n_in,
                              void* d_out, int out_size, void* d_ws,
                              size_t ws_size, hipStream_t stream) {
  const int* curr_pos = (const int*)d_in[0];
  const float* z_curr = (const float*)d_in[1];
  const float* z_past = (const float*)d_in[2];
  const float* Wq = (const float*)d_in[3];
  const float* bq = (const float*)d_in[4];
  const float* Wk = (const float*)d_in[5];
  const float* bk = (const float*)d_in[6];
  const float* Wv = (const float*)d_in[7];
  const float* bv = (const float*)d_in[8];
  const float* Wo = (const float*)d_in[9];
  const float* bo = (const float*)d_in[10];
  const float* rb = (const float*)d_in[11];
  float* out = (float*)d_out;

  const int L = in_sizes[2] / 512;
  const int nb = (L + 127) / 128;  // attn blocks (128 rows each)

  float* ws = (float*)d_ws;
  size_t o = 0;
  float* qp = ws + o;       o += 512;
  float* wkb = ws + o;      o += 8 * 512;
  float* ckb = ws + o;      o += 16;
  float* relq = ws + o;     o += 1040;
  float* sb = ws + o;       o += 8;
  float* sp = ws + o;       o += (size_t)nb * 8;
  float* S_un = ws + o;     o += 4096;
  float* out_real = ws + o; o += 512;
  float* Sp = ws + o;       o += (size_t)nb * 4096;
  (void)ws_size; (void)n_in; (void)out_size;

  k_matvec512<<<128, 256, 0, stream>>>(Wq, z_curr, bq, qp);
  k_front2<<<24, 256, 0, stream>>>(Wk, qp, bk, rb, wkb, ckb, relq, S_un);
  k_attn<<<nb, 256, 0, stream>>>(z_past, wkb, ckb, relq, curr_pos, L, Sp, sp);
  k_comb2<<<257, 256, 0, stream>>>(Sp, sp, nb, S_un, sb);
  k_outreal<<<128, 256, 0, stream>>>(Wv, S_un, sb, bv, out_real);
  k_matvec512<<<128, 256, 0, stream>>>(Wo, out_real, bo, out);
}

// Round 4
// 255.712 us; speedup vs baseline: 1.0029x; 1.0029x over previous
//
#include <hip/hip_runtime.h>
#include <math.h>

// MultiHeadModulator: single-query complex multi-head attention over L=65536
// past positions, dim=256 (d2=512 real), H=8 heads.
//
// Algebraic reduction (k_proj/v_proj never materialized):
//   scores[l,h] = sum_i z[l,i]*wk[h,i] + ck[h] + relq[idx(l),h]
//   S_un[h,i]   = sum_l exp(scores[l,h]) * z[l,i]     (no max-sub: scores ~N(0,0.5))
//   s[h]        = sum_l exp(scores[l,h])
//   out_real[j] = sum_i Wv[j,i]*S_un[h(j),i]/s[h(j)] + bv[j]
//   out[j']     = sum_j Wo[j',j]*out_real[j] + bo[j']
//
// v5 (unbundle): regression ledger vs v1=243.4 (cross-run noise ~±1us):
//   v2 (front2+depth2+direct-atomic)  +17.0
//   v3 (front2+slotted-atomic)         +9.1
//   v4 (front2+depth2+Sp/comb2)       +13.1
// Atomic combine: confirmed dead end. v4 isolates front2+depth2=+13.1; prime
// suspect is depth-2 prefetch: k_attn's live set (~wkr64+S64+temps) is near
// the 256-VGPR cap of __launch_bounds__(256,2); +8 regs under unroll-2 =>
// scratch spills in the hot loop. front2 has no regression mechanism (same
// traffic, one FEWER launch). So: exact v1 kernels (depth-1 attn, streaming
// Sp+comb2) + front2 fusion ONLY. This both unbundles the confound and is
// the only mechanically-safe saving (launch elimination).

static constexpr float SCALE = 0.17677669529663687f; // 1/sqrt(32)

__device__ __forceinline__ float wave_sum(float v) {
#pragma unroll
  for (int off = 32; off > 0; off >>= 1) v += __shfl_xor(v, off, 64);
  return v;
}

// y[j] = bias[j] + sum_i x[i]*M[j*512+i], 512 rows, one wave per row. grid=128
__global__ __launch_bounds__(256) void k_matvec512(
    const float* __restrict__ M, const float* __restrict__ x,
    const float* __restrict__ bias, float* __restrict__ y) {
  const int wave = threadIdx.x >> 6, lane = threadIdx.x & 63;
  const int j = blockIdx.x * 4 + wave;
  const float* Mr = M + (size_t)j * 512 + lane * 8;
  const float4 m0 = *(const float4*)Mr;
  const float4 m1 = *(const float4*)(Mr + 4);
  const float4 x0 = *(const float4*)(x + lane * 8);
  const float4 x1 = *(const float4*)(x + lane * 8 + 4);
  float acc = m0.x * x0.x + m0.y * x0.y + m0.z * x0.z + m0.w * x0.w +
              m1.x * x1.x + m1.y * x1.y + m1.z * x1.z + m1.w * x1.w;
  acc = wave_sum(acc);
  if (lane == 0) y[j] = acc + bias[j];
}

// Fused front-end stage 2 (needs qp). grid = 24:
//  blocks 0..15 : wk[h,i] = SCALE * sum_{k<64} qp[h*64+k]*Wk[(h*64+k)*512+i]
//                 (block b: h=b>>1, i=(b&1)*256+tid; single-stage)
//  blocks 16..21: relq[idx*8+h] = SCALE * sum_k qp[h*64+k]*rb[idx*512+h*64+k]
//  block 22     : ck[h] = SCALE * sum_k qp[h*64+k]*bk[h*64+k]
//  block 23     : zero S_un[4096]
__global__ __launch_bounds__(256) void k_front2(
    const float* __restrict__ Wk, const float* __restrict__ qp,
    const float* __restrict__ bk, const float* __restrict__ rb,
    float* __restrict__ wk, float* __restrict__ ck, float* __restrict__ relq,
    float* __restrict__ S_un) {
  __shared__ float ql[512];
  const int b = blockIdx.x;
  if (b < 16) {
    const int h = b >> 1;
    if (threadIdx.x < 64) ql[threadIdx.x] = qp[h * 64 + threadIdx.x];
    __syncthreads();
    const int i = (b & 1) * 256 + threadIdx.x;
    float acc = 0.f;
#pragma unroll
    for (int k = 0; k < 64; ++k)
      acc += ql[k] * Wk[(size_t)(h * 64 + k) * 512 + i];
    wk[h * 512 + i] = acc * SCALE;
  } else if (b < 22) {
    for (int t = threadIdx.x; t < 512; t += 256) ql[t] = qp[t];
    __syncthreads();
    const int t = (b - 16) * 256 + threadIdx.x;
    if (t < 129 * 8) {
      const int idx = t >> 3, h = t & 7;
      float acc = 0.f;
#pragma unroll
      for (int k = 0; k < 64; ++k)
        acc += ql[h * 64 + k] * rb[(size_t)idx * 512 + h * 64 + k];
      relq[t] = acc * SCALE;
    }
  } else if (b == 22) {
    if (threadIdx.x < 8) {
      const int h = threadIdx.x;
      float acc = 0.f;
      for (int k = 0; k < 64; ++k) acc += qp[h * 64 + k] * bk[h * 64 + k];
      ck[h] = acc * SCALE;
    }
  } else {
    for (int t = threadIdx.x; t < 4096; t += 256) S_un[t] = 0.f;
  }
}

// Fused single pass: scores + exp + weighted z accumulation.
// 128 rows/block (32/wave), grid = L/128 = 512 -> 2 blocks/CU.
// EXACT v1 body: depth-1 register prefetch (depth-2 suspected of VGPR spills
// past the 256-cap of __launch_bounds__(256,2)).
__global__ __launch_bounds__(256, 2) void k_attn(
    const float* __restrict__ zp, const float* __restrict__ wk,
    const float* __restrict__ ck, const float* __restrict__ relq,
    const int* __restrict__ curr_pos, int L, float* __restrict__ Sp,
    float* __restrict__ sp) {
  __shared__ float relql[1032];
  __shared__ float Sl[4096];
  __shared__ float sl[4][8];
  const int tid = threadIdx.x;
  const int wave = tid >> 6, lane = tid & 63;
  for (int t = tid; t < 1032; t += 256) relql[t] = relq[t];

  float wkr[8][8];
#pragma unroll
  for (int h = 0; h < 8; ++h) {
    const float4 a = *(const float4*)(wk + h * 512 + lane * 8);
    const float4 b = *(const float4*)(wk + h * 512 + lane * 8 + 4);
    wkr[h][0] = a.x; wkr[h][1] = a.y; wkr[h][2] = a.z; wkr[h][3] = a.w;
    wkr[h][4] = b.x; wkr[h][5] = b.y; wkr[h][6] = b.z; wkr[h][7] = b.w;
  }
  // fold-reduce leaves lane holding head myh = bitrev3(lane&7)
  const int myh = ((lane & 1) << 2) | (lane & 2) | ((lane >> 2) & 1);
  const float ck_my = ck[myh];
  const int cp = curr_pos[0];
  __syncthreads();

  float S[8][8];
#pragma unroll
  for (int h = 0; h < 8; ++h)
#pragma unroll
    for (int k = 0; k < 8; ++k) S[h][k] = 0.f;
  float s_loc = 0.f;

  const int l0 = blockIdx.x * 128 + wave * 32;
  const float* zr = zp + (size_t)l0 * 512 + lane * 8;
  float4 p0 = *(const float4*)zr;
  float4 p1 = *(const float4*)(zr + 4);

#pragma unroll 2
  for (int r = 0; r < 32; ++r) {
    const int l = l0 + r;
    // register prefetch of next row (clamped at the very end)
    const float* zn = (l + 1 < L) ? (zr + 512) : zr;
    const float4 n0 = *(const float4*)zn;
    const float4 n1 = *(const float4*)(zn + 4);
    const float zz[8] = {p0.x, p0.y, p0.z, p0.w, p1.x, p1.y, p1.z, p1.w};
    float acc[8];
#pragma unroll
    for (int h = 0; h < 8; ++h) {
      float a = 0.f;
#pragma unroll
      for (int k = 0; k < 8; ++k) a += zz[k] * wkr[h][k];
      acc[h] = a;
    }
    // fold-reduce: 8 values across 64 lanes in 10 shuffles
    const bool lo1 = (lane & 1) == 0;
    float b0 = (lo1 ? acc[0] : acc[4]) + __shfl_xor(lo1 ? acc[4] : acc[0], 1, 64);
    float b1 = (lo1 ? acc[1] : acc[5]) + __shfl_xor(lo1 ? acc[5] : acc[1], 1, 64);
    float b2 = (lo1 ? acc[2] : acc[6]) + __shfl_xor(lo1 ? acc[6] : acc[2], 1, 64);
    float b3 = (lo1 ? acc[3] : acc[7]) + __shfl_xor(lo1 ? acc[7] : acc[3], 1, 64);
    const bool lo2 = (lane & 2) == 0;
    float c0 = (lo2 ? b0 : b2) + __shfl_xor(lo2 ? b2 : b0, 2, 64);
    float c1 = (lo2 ? b1 : b3) + __shfl_xor(lo2 ? b3 : b1, 2, 64);
    const bool lo3 = (lane & 4) == 0;
    float d = (lo3 ? c0 : c1) + __shfl_xor(lo3 ? c1 : c0, 4, 64);
    d += __shfl_xor(d, 8, 64);
    d += __shfl_xor(d, 16, 64);
    d += __shfl_xor(d, 32, 64);

    int dd = cp - L + l + 64;
    dd = dd < 0 ? 0 : (dd > 128 ? 128 : dd);
    float w = __expf(d + ck_my + relql[dd * 8 + myh]);
    if (l >= L) w = 0.f;
    s_loc += w;
#pragma unroll
    for (int h = 0; h < 8; ++h) {
      const int src = ((h & 1) << 2) | (h & 2) | ((h >> 2) & 1);
      const float wh = __shfl(w, src, 64);
#pragma unroll
      for (int k = 0; k < 8; ++k) S[h][k] += wh * zz[k];
    }
    p0 = n0; p1 = n1; zr += 512;
  }

  if (lane < 8) sl[wave][myh] = s_loc;
  // merge the 4 waves' register tiles into LDS
  for (int wv = 0; wv < 4; ++wv) {
    if (wave == wv) {
#pragma unroll
      for (int h = 0; h < 8; ++h)
#pragma unroll
        for (int k = 0; k < 8; ++k) {
          const int idx = h * 512 + lane * 8 + k;
          if (wv == 0) Sl[idx] = S[h][k];
          else Sl[idx] += S[h][k];
        }
    }
    __syncthreads();
  }
  for (int t = tid; t < 4096; t += 256)
    Sp[(size_t)blockIdx.x * 4096 + t] = Sl[t];
  if (tid < 8)
    sp[blockIdx.x * 8 + tid] = sl[0][tid] + sl[1][tid] + sl[2][tid] + sl[3][tid];
}

// combine block partials. blocks 0..255: S_un (atomic, pre-zeroed);
// block 256: s. grid=257
__global__ __launch_bounds__(256) void k_comb2(
    const float* __restrict__ Sp, const float* __restrict__ spv, int nb,
    float* __restrict__ S_un, float* __restrict__ s) {
  if (blockIdx.x < 256) {
    const int T = blockIdx.x * 256 + threadIdx.x;
    const int col = T & 4095;
    const int g = T >> 12;  // 0..15
    const int chunk = (nb + 15) >> 4;
    const int r0 = g * chunk;
    const int r1 = min(r0 + chunk, nb);
    float a[8];
#pragma unroll
    for (int u = 0; u < 8; ++u) a[u] = 0.f;
    int b = r0;
    for (; b + 8 <= r1; b += 8) {
#pragma unroll
      for (int u = 0; u < 8; ++u) a[u] += Sp[(size_t)(b + u) * 4096 + col];
    }
    for (; b < r1; ++b) a[0] += Sp[(size_t)b * 4096 + col];
    const float t = ((a[0] + a[1]) + (a[2] + a[3])) +
                    ((a[4] + a[5]) + (a[6] + a[7]));
    atomicAdd(&S_un[col], t);
  } else {
    __shared__ float red[256];
    float a = 0.f;
    for (int b2 = threadIdx.x >> 3; b2 < nb; b2 += 32)
      a += spv[b2 * 8 + (threadIdx.x & 7)];
    red[threadIdx.x] = a;
    __syncthreads();
    if (threadIdx.x < 8) {
      float x = 0.f;
      for (int c = 0; c < 32; ++c) x += red[c * 8 + threadIdx.x];
      s[threadIdx.x] = x;
    }
  }
}

// out_real[j] = bv[j] + (sum_i Wv[j,i]*S_un[h(j),i]) / s[h(j)]. grid=128
__global__ __launch_bounds__(256) void k_outreal(
    const float* __restrict__ Wv, const float* __restrict__ S_un,
    const float* __restrict__ s, const float* __restrict__ bv,
    float* __restrict__ out_real) {
  const int wave = threadIdx.x >> 6, lane = threadIdx.x & 63;
  const int j = blockIdx.x * 4 + wave;
  const int h = j >> 6;
  const float* Mr = Wv + (size_t)j * 512 + lane * 8;
  const float* xr = S_un + h * 512 + lane * 8;
  const float4 m0 = *(const float4*)Mr;
  const float4 m1 = *(const float4*)(Mr + 4);
  const float4 x0 = *(const float4*)xr;
  const float4 x1 = *(const float4*)(xr + 4);
  float acc = m0.x * x0.x + m0.y * x0.y + m0.z * x0.z + m0.w * x0.w +
              m1.x * x1.x + m1.y * x1.y + m1.z * x1.z + m1.w * x1.w;
  acc = wave_sum(acc);
  if (lane == 0) out_real[j] = acc / s[h] + bv[j];
}

extern "C" void kernel_launch(void* const* d_in, const int* in_sizes, int n_in,
                              void* d_out, int out_size, void* d_ws,
                              size_t ws_size, hipStream_t stream) {
  const int* curr_pos = (const int*)d_in[0];
  const float* z_curr = (const float*)d_in[1];
  const float* z_past = (const float*)d_in[2];
  const float* Wq = (const float*)d_in[3];
  const float* bq = (const float*)d_in[4];
  const float* Wk = (const float*)d_in[5];
  const float* bk = (const float*)d_in[6];
  const float* Wv = (const float*)d_in[7];
  const float* bv = (const float*)d_in[8];
  const float* Wo = (const float*)d_in[9];
  const float* bo = (const float*)d_in[10];
  const float* rb = (const float*)d_in[11];
  float* out = (float*)d_out;

  const int L = in_sizes[2] / 512;
  const int nb = (L + 127) / 128;  // attn blocks (128 rows each)

  float* ws = (float*)d_ws;
  size_t o = 0;
  float* qp = ws + o;       o += 512;
  float* wkb = ws + o;      o += 8 * 512;
  float* ckb = ws + o;      o += 16;
  float* relq = ws + o;     o += 1040;
  float* sb = ws + o;       o += 8;
  float* sp = ws + o;       o += (size_t)nb * 8;
  float* S_un = ws + o;     o += 4096;
  float* out_real = ws + o; o += 512;
  float* Sp = ws + o;       o += (size_t)nb * 4096;
  (void)ws_size; (void)n_in; (void)out_size;

  k_matvec512<<<128, 256, 0, stream>>>(Wq, z_curr, bq, qp);
  k_front2<<<24, 256, 0, stream>>>(Wk, qp, bk, rb, wkb, ckb, relq, S_un);
  k_attn<<<nb, 256, 0, stream>>>(z_past, wkb, ckb, relq, curr_pos, L, Sp, sp);
  k_comb2<<<257, 256, 0, stream>>>(Sp, sp, nb, S_un, sb);
  k_outreal<<<128, 256, 0, stream>>>(Wv, S_un, sb, bv, out_real);
  k_matvec512<<<128, 256, 0, stream>>>(Wo, out_real, bo, out);
}

// Round 5
// 243.325 us; speedup vs baseline: 1.0540x; 1.0509x over previous
//
#include <hip/hip_runtime.h>
#include <math.h>

// MultiHeadModulator: single-query complex multi-head attention over L=65536
// past positions, dim=256 (d2=512 real), H=8 heads.
//
// Algebraic reduction (k_proj/v_proj never materialized):
//   scores[l,h] = sum_i z[l,i]*wk[h,i] + ck[h] + relq[idx(l),h]
//   S_un[h,i]   = sum_l exp(scores[l,h]) * z[l,i]     (no max-sub: scores ~N(0,0.5))
//   s[h]        = sum_l exp(scores[l,h])
//   out_real[j] = sum_i Wv[j,i]*S_un[h(j),i]/s[h(j)] + bv[j]
//   out[j']     = sum_j Wo[j',j]*out_real[j] + bo[j']
//
// v6 = byte-identical revert to v1 (the 243.4/244.0 us config).
// Ledger vs v1=243.4: v2 +17.0, v3 +9.1, v4 +13.1, v5(front2 only) +12.3.
// A single parameter "front2 = +12us" fits ALL four rounds (residual <= 3us);
// front2 has no traffic-level mechanism, so the suspects are (a) module-level
// codegen perturbation of k_attn (co-compiled kernels share regalloc context)
// or (b) baseline environment drift since the round-0 measurement. This run
// is the discriminating A/B: ~243-246 => front2 guilty, keep this structure;
// ~252-257 => drift, re-anchor.

static constexpr float SCALE = 0.17677669529663687f; // 1/sqrt(32)

__device__ __forceinline__ float wave_sum(float v) {
#pragma unroll
  for (int off = 32; off > 0; off >>= 1) v += __shfl_xor(v, off, 64);
  return v;
}

// y[j] = bias[j] + sum_i x[i]*M[j*512+i], 512 rows, one wave per row. grid=128
__global__ __launch_bounds__(256) void k_matvec512(
    const float* __restrict__ M, const float* __restrict__ x,
    const float* __restrict__ bias, float* __restrict__ y) {
  const int wave = threadIdx.x >> 6, lane = threadIdx.x & 63;
  const int j = blockIdx.x * 4 + wave;
  const float* Mr = M + (size_t)j * 512 + lane * 8;
  const float4 m0 = *(const float4*)Mr;
  const float4 m1 = *(const float4*)(Mr + 4);
  const float4 x0 = *(const float4*)(x + lane * 8);
  const float4 x1 = *(const float4*)(x + lane * 8 + 4);
  float acc = m0.x * x0.x + m0.y * x0.y + m0.z * x0.z + m0.w * x0.w +
              m1.x * x1.x + m1.y * x1.y + m1.z * x1.z + m1.w * x1.w;
  acc = wave_sum(acc);
  if (lane == 0) y[j] = acc + bias[j];
}

// wkpart[b,i] = sum_{j in [32b,32b+32)} qp[j]*Wk[j,i].  grid=16
__global__ __launch_bounds__(256) void k_wkpart(
    const float* __restrict__ Wk, const float* __restrict__ qp,
    float* __restrict__ wkpart) {
  __shared__ float ql[32];
  const int b = blockIdx.x;
  if (threadIdx.x < 32) ql[threadIdx.x] = qp[b * 32 + threadIdx.x];
  __syncthreads();
  for (int i = threadIdx.x; i < 512; i += 256) {
    float acc = 0.f;
#pragma unroll
    for (int k = 0; k < 32; ++k)
      acc += ql[k] * Wk[(size_t)(b * 32 + k) * 512 + i];
    wkpart[b * 512 + i] = acc;
  }
}

// blocks 0..7: wk; block 8: ck; blocks 9..13: relq; block 14: zero S_un. grid=15
__global__ __launch_bounds__(256) void k_misc(
    const float* __restrict__ qp, const float* __restrict__ bk,
    const float* __restrict__ rb, const float* __restrict__ wkpart,
    float* __restrict__ wk, float* __restrict__ ck, float* __restrict__ relq,
    float* __restrict__ S_un) {
  const int b = blockIdx.x;
  if (b < 8) {
    for (int i = threadIdx.x; i < 512; i += 256)
      wk[b * 512 + i] =
          (wkpart[(2 * b) * 512 + i] + wkpart[(2 * b + 1) * 512 + i]) * SCALE;
  } else if (b == 8) {
    if (threadIdx.x < 8) {
      const int h = threadIdx.x;
      float acc = 0.f;
      for (int k = 0; k < 64; ++k) acc += qp[h * 64 + k] * bk[h * 64 + k];
      ck[h] = acc * SCALE;
    }
  } else if (b < 14) {
    const int t = (b - 9) * 256 + threadIdx.x;
    if (t < 129 * 8) {
      const int idx = t >> 3, h = t & 7;
      float acc = 0.f;
      for (int k = 0; k < 64; ++k)
        acc += qp[h * 64 + k] * rb[(size_t)idx * 512 + h * 64 + k];
      relq[t] = acc * SCALE;
    }
  } else {
    for (int t = threadIdx.x; t < 4096; t += 256) S_un[t] = 0.f;
  }
}

// Fused single pass: scores + exp + weighted z accumulation.
// 128 rows/block (32/wave), grid = L/128 = 512 -> 2 blocks/CU.
__global__ __launch_bounds__(256, 2) void k_attn(
    const float* __restrict__ zp, const float* __restrict__ wk,
    const float* __restrict__ ck, const float* __restrict__ relq,
    const int* __restrict__ curr_pos, int L, float* __restrict__ Sp,
    float* __restrict__ sp) {
  __shared__ float relql[1032];
  __shared__ float Sl[4096];
  __shared__ float sl[4][8];
  const int tid = threadIdx.x;
  const int wave = tid >> 6, lane = tid & 63;
  for (int t = tid; t < 1032; t += 256) relql[t] = relq[t];

  float wkr[8][8];
#pragma unroll
  for (int h = 0; h < 8; ++h) {
    const float4 a = *(const float4*)(wk + h * 512 + lane * 8);
    const float4 b = *(const float4*)(wk + h * 512 + lane * 8 + 4);
    wkr[h][0] = a.x; wkr[h][1] = a.y; wkr[h][2] = a.z; wkr[h][3] = a.w;
    wkr[h][4] = b.x; wkr[h][5] = b.y; wkr[h][6] = b.z; wkr[h][7] = b.w;
  }
  // fold-reduce leaves lane holding head myh = bitrev3(lane&7)
  const int myh = ((lane & 1) << 2) | (lane & 2) | ((lane >> 2) & 1);
  const float ck_my = ck[myh];
  const int cp = curr_pos[0];
  __syncthreads();

  float S[8][8];
#pragma unroll
  for (int h = 0; h < 8; ++h)
#pragma unroll
    for (int k = 0; k < 8; ++k) S[h][k] = 0.f;
  float s_loc = 0.f;

  const int l0 = blockIdx.x * 128 + wave * 32;
  const float* zr = zp + (size_t)l0 * 512 + lane * 8;
  float4 p0 = *(const float4*)zr;
  float4 p1 = *(const float4*)(zr + 4);

#pragma unroll 2
  for (int r = 0; r < 32; ++r) {
    const int l = l0 + r;
    // register prefetch of next row (clamped at the very end)
    const float* zn = (l + 1 < L) ? (zr + 512) : zr;
    const float4 n0 = *(const float4*)zn;
    const float4 n1 = *(const float4*)(zn + 4);
    const float zz[8] = {p0.x, p0.y, p0.z, p0.w, p1.x, p1.y, p1.z, p1.w};
    float acc[8];
#pragma unroll
    for (int h = 0; h < 8; ++h) {
      float a = 0.f;
#pragma unroll
      for (int k = 0; k < 8; ++k) a += zz[k] * wkr[h][k];
      acc[h] = a;
    }
    // fold-reduce: 8 values across 64 lanes in 10 shuffles
    const bool lo1 = (lane & 1) == 0;
    float b0 = (lo1 ? acc[0] : acc[4]) + __shfl_xor(lo1 ? acc[4] : acc[0], 1, 64);
    float b1 = (lo1 ? acc[1] : acc[5]) + __shfl_xor(lo1 ? acc[5] : acc[1], 1, 64);
    float b2 = (lo1 ? acc[2] : acc[6]) + __shfl_xor(lo1 ? acc[6] : acc[2], 1, 64);
    float b3 = (lo1 ? acc[3] : acc[7]) + __shfl_xor(lo1 ? acc[7] : acc[3], 1, 64);
    const bool lo2 = (lane & 2) == 0;
    float c0 = (lo2 ? b0 : b2) + __shfl_xor(lo2 ? b2 : b0, 2, 64);
    float c1 = (lo2 ? b1 : b3) + __shfl_xor(lo2 ? b3 : b1, 2, 64);
    const bool lo3 = (lane & 4) == 0;
    float d = (lo3 ? c0 : c1) + __shfl_xor(lo3 ? c1 : c0, 4, 64);
    d += __shfl_xor(d, 8, 64);
    d += __shfl_xor(d, 16, 64);
    d += __shfl_xor(d, 32, 64);

    int dd = cp - L + l + 64;
    dd = dd < 0 ? 0 : (dd > 128 ? 128 : dd);
    float w = __expf(d + ck_my + relql[dd * 8 + myh]);
    if (l >= L) w = 0.f;
    s_loc += w;
#pragma unroll
    for (int h = 0; h < 8; ++h) {
      const int src = ((h & 1) << 2) | (h & 2) | ((h >> 2) & 1);
      const float wh = __shfl(w, src, 64);
#pragma unroll
      for (int k = 0; k < 8; ++k) S[h][k] += wh * zz[k];
    }
    p0 = n0; p1 = n1; zr += 512;
  }

  if (lane < 8) sl[wave][myh] = s_loc;
  // merge the 4 waves' register tiles into LDS
  for (int wv = 0; wv < 4; ++wv) {
    if (wave == wv) {
#pragma unroll
      for (int h = 0; h < 8; ++h)
#pragma unroll
        for (int k = 0; k < 8; ++k) {
          const int idx = h * 512 + lane * 8 + k;
          if (wv == 0) Sl[idx] = S[h][k];
          else Sl[idx] += S[h][k];
        }
    }
    __syncthreads();
  }
  for (int t = tid; t < 4096; t += 256)
    Sp[(size_t)blockIdx.x * 4096 + t] = Sl[t];
  if (tid < 8)
    sp[blockIdx.x * 8 + tid] = sl[0][tid] + sl[1][tid] + sl[2][tid] + sl[3][tid];
}

// combine block partials. blocks 0..255: S_un (atomic, pre-zeroed);
// block 256: s. grid=257
__global__ __launch_bounds__(256) void k_comb2(
    const float* __restrict__ Sp, const float* __restrict__ spv, int nb,
    float* __restrict__ S_un, float* __restrict__ s) {
  if (blockIdx.x < 256) {
    const int T = blockIdx.x * 256 + threadIdx.x;
    const int col = T & 4095;
    const int g = T >> 12;  // 0..15
    const int chunk = (nb + 15) >> 4;
    const int r0 = g * chunk;
    const int r1 = min(r0 + chunk, nb);
    float a[8];
#pragma unroll
    for (int u = 0; u < 8; ++u) a[u] = 0.f;
    int b = r0;
    for (; b + 8 <= r1; b += 8) {
#pragma unroll
      for (int u = 0; u < 8; ++u) a[u] += Sp[(size_t)(b + u) * 4096 + col];
    }
    for (; b < r1; ++b) a[0] += Sp[(size_t)b * 4096 + col];
    const float t = ((a[0] + a[1]) + (a[2] + a[3])) +
                    ((a[4] + a[5]) + (a[6] + a[7]));
    atomicAdd(&S_un[col], t);
  } else {
    __shared__ float red[256];
    float a = 0.f;
    for (int b2 = threadIdx.x >> 3; b2 < nb; b2 += 32)
      a += spv[b2 * 8 + (threadIdx.x & 7)];
    red[threadIdx.x] = a;
    __syncthreads();
    if (threadIdx.x < 8) {
      float x = 0.f;
      for (int c = 0; c < 32; ++c) x += red[c * 8 + threadIdx.x];
      s[threadIdx.x] = x;
    }
  }
}

// out_real[j] = bv[j] + (sum_i Wv[j,i]*S_un[h(j),i]) / s[h(j)]. grid=128
__global__ __launch_bounds__(256) void k_outreal(
    const float* __restrict__ Wv, const float* __restrict__ S_un,
    const float* __restrict__ s, const float* __restrict__ bv,
    float* __restrict__ out_real) {
  const int wave = threadIdx.x >> 6, lane = threadIdx.x & 63;
  const int j = blockIdx.x * 4 + wave;
  const int h = j >> 6;
  const float* Mr = Wv + (size_t)j * 512 + lane * 8;
  const float* xr = S_un + h * 512 + lane * 8;
  const float4 m0 = *(const float4*)Mr;
  const float4 m1 = *(const float4*)(Mr + 4);
  const float4 x0 = *(const float4*)xr;
  const float4 x1 = *(const float4*)(xr + 4);
  float acc = m0.x * x0.x + m0.y * x0.y + m0.z * x0.z + m0.w * x0.w +
              m1.x * x1.x + m1.y * x1.y + m1.z * x1.z + m1.w * x1.w;
  acc = wave_sum(acc);
  if (lane == 0) out_real[j] = acc / s[h] + bv[j];
}

extern "C" void kernel_launch(void* const* d_in, const int* in_sizes, int n_in,
                              void* d_out, int out_size, void* d_ws,
                              size_t ws_size, hipStream_t stream) {
  const int* curr_pos = (const int*)d_in[0];
  const float* z_curr = (const float*)d_in[1];
  const float* z_past = (const float*)d_in[2];
  const float* Wq = (const float*)d_in[3];
  const float* bq = (const float*)d_in[4];
  const float* Wk = (const float*)d_in[5];
  const float* bk = (const float*)d_in[6];
  const float* Wv = (const float*)d_in[7];
  const float* bv = (const float*)d_in[8];
  const float* Wo = (const float*)d_in[9];
  const float* bo = (const float*)d_in[10];
  const float* rb = (const float*)d_in[11];
  float* out = (float*)d_out;

  const int L = in_sizes[2] / 512;
  const int nb = (L + 127) / 128;  // attn blocks (128 rows each)

  float* ws = (float*)d_ws;
  size_t o = 0;
  float* qp = ws + o;       o += 512;
  float* wkpart = ws + o;   o += 16 * 512;
  float* wk = ws + o;       o += 8 * 512;
  float* ck = ws + o;       o += 16;
  float* relq = ws + o;     o += 1040;
  float* s = ws + o;        o += 8;
  float* sp = ws + o;       o += (size_t)nb * 8;
  float* S_un = ws + o;     o += 4096;
  float* out_real = ws + o; o += 512;
  float* Sp = ws + o;       o += (size_t)nb * 4096;
  (void)ws_size; (void)n_in; (void)out_size;

  k_matvec512<<<128, 256, 0, stream>>>(Wq, z_curr, bq, qp);
  k_wkpart<<<16, 256, 0, stream>>>(Wk, qp, wkpart);
  k_misc<<<15, 256, 0, stream>>>(qp, bk, rb, wkpart, wk, ck, relq, S_un);
  k_attn<<<nb, 256, 0, stream>>>(z_past, wk, ck, relq, curr_pos, L, Sp, sp);
  k_comb2<<<257, 256, 0, stream>>>(Sp, sp, nb, S_un, s);
  k_outreal<<<128, 256, 0, stream>>>(Wv, S_un, s, bv, out_real);
  k_matvec512<<<128, 256, 0, stream>>>(Wo, out_real, bo, out);
}

// Round 6
// 238.058 us; speedup vs baseline: 1.0773x; 1.0221x over previous
//
#include <hip/hip_runtime.h>
#include <math.h>

// MultiHeadModulator: single-query complex multi-head attention over L=65536
// past positions, dim=256 (d2=512 real), H=8 heads.
//
// Algebraic reduction (k_proj/v_proj never materialized):
//   scores[l,h] = sum_i z[l,i]*wk[h,i] + ck[h] + relq[idx(l),h]
//   S_un[h,i]   = sum_l exp(scores[l,h]) * z[l,i]     (no max-sub: scores ~N(0,0.5))
//   s[h]        = sum_l exp(scores[l,h])
//   out_real[j] = sum_i Wv[j,i]*S_un[h(j),i]/s[h(j)] + bv[j]
//   out[j']     = sum_j Wo[j',j]*out_real[j] + bo[j']
//
// v7: ledger (v1=243.3 reproduced 3x, noise ±1): front2-fusion = +12 (real,
// mechanism unidentified -- suspected co-compilation codegen perturbation);
// direct-atomic = +5; depth2 = +1; slotted-atomic = -3 (fitted). This round:
// v1 front-end byte-identical (matvec, wkpart, misc-main, attn main loop),
// ONLY the combine changed to v3's validated slotted scheme:
//   - k_attn tail: atomicAdd into S_un slot (blockIdx&15), chain depth 32
//   - k_misc grid 15->30: blocks 14..29 zero one 16KB slot each
//   - k_comb2 deleted; k_outreal folds 16 slots (L2-resident)
// 6 launches, no 16MB Sp round-trip.

static constexpr float SCALE = 0.17677669529663687f; // 1/sqrt(32)
static constexpr int NSLOT = 16;                     // accumulator slots

__device__ __forceinline__ float wave_sum(float v) {
#pragma unroll
  for (int off = 32; off > 0; off >>= 1) v += __shfl_xor(v, off, 64);
  return v;
}

// y[j] = bias[j] + sum_i x[i]*M[j*512+i], 512 rows, one wave per row. grid=128
__global__ __launch_bounds__(256) void k_matvec512(
    const float* __restrict__ M, const float* __restrict__ x,
    const float* __restrict__ bias, float* __restrict__ y) {
  const int wave = threadIdx.x >> 6, lane = threadIdx.x & 63;
  const int j = blockIdx.x * 4 + wave;
  const float* Mr = M + (size_t)j * 512 + lane * 8;
  const float4 m0 = *(const float4*)Mr;
  const float4 m1 = *(const float4*)(Mr + 4);
  const float4 x0 = *(const float4*)(x + lane * 8);
  const float4 x1 = *(const float4*)(x + lane * 8 + 4);
  float acc = m0.x * x0.x + m0.y * x0.y + m0.z * x0.z + m0.w * x0.w +
              m1.x * x1.x + m1.y * x1.y + m1.z * x1.z + m1.w * x1.w;
  acc = wave_sum(acc);
  if (lane == 0) y[j] = acc + bias[j];
}

// wkpart[b,i] = sum_{j in [32b,32b+32)} qp[j]*Wk[j,i].  grid=16
__global__ __launch_bounds__(256) void k_wkpart(
    const float* __restrict__ Wk, const float* __restrict__ qp,
    float* __restrict__ wkpart) {
  __shared__ float ql[32];
  const int b = blockIdx.x;
  if (threadIdx.x < 32) ql[threadIdx.x] = qp[b * 32 + threadIdx.x];
  __syncthreads();
  for (int i = threadIdx.x; i < 512; i += 256) {
    float acc = 0.f;
#pragma unroll
    for (int k = 0; k < 32; ++k)
      acc += ql[k] * Wk[(size_t)(b * 32 + k) * 512 + i];
    wkpart[b * 512 + i] = acc;
  }
}

// blocks 0..7: wk; block 8: ck; blocks 9..13: relq;
// blocks 14..29: zero S_un slot (b-14) and s slot (b-14). grid=30
__global__ __launch_bounds__(256) void k_misc(
    const float* __restrict__ qp, const float* __restrict__ bk,
    const float* __restrict__ rb, const float* __restrict__ wkpart,
    float* __restrict__ wk, float* __restrict__ ck, float* __restrict__ relq,
    float* __restrict__ S_un, float* __restrict__ s) {
  const int b = blockIdx.x;
  if (b < 8) {
    for (int i = threadIdx.x; i < 512; i += 256)
      wk[b * 512 + i] =
          (wkpart[(2 * b) * 512 + i] + wkpart[(2 * b + 1) * 512 + i]) * SCALE;
  } else if (b == 8) {
    if (threadIdx.x < 8) {
      const int h = threadIdx.x;
      float acc = 0.f;
      for (int k = 0; k < 64; ++k) acc += qp[h * 64 + k] * bk[h * 64 + k];
      ck[h] = acc * SCALE;
    }
  } else if (b < 14) {
    const int t = (b - 9) * 256 + threadIdx.x;
    if (t < 129 * 8) {
      const int idx = t >> 3, h = t & 7;
      float acc = 0.f;
      for (int k = 0; k < 64; ++k)
        acc += qp[h * 64 + k] * rb[(size_t)idx * 512 + h * 64 + k];
      relq[t] = acc * SCALE;
    }
  } else {
    const int sl = b - 14;
    for (int t = threadIdx.x; t < 4096; t += 256) S_un[sl * 4096 + t] = 0.f;
    if (threadIdx.x < 8) s[sl * 8 + threadIdx.x] = 0.f;
  }
}

// Fused single pass: scores + exp + weighted z accumulation.
// 128 rows/block (32/wave), grid = L/128 = 512 -> 2 blocks/CU.
// Tail: 4-wave LDS merge, then atomicAdd into slot (blockIdx & 15) of S_un/s.
__global__ __launch_bounds__(256, 2) void k_attn(
    const float* __restrict__ zp, const float* __restrict__ wk,
    const float* __restrict__ ck, const float* __restrict__ relq,
    const int* __restrict__ curr_pos, int L, float* __restrict__ S_un,
    float* __restrict__ s_out) {
  __shared__ float relql[1032];
  __shared__ float Sl[4096];
  __shared__ float sl[4][8];
  const int tid = threadIdx.x;
  const int wave = tid >> 6, lane = tid & 63;
  for (int t = tid; t < 1032; t += 256) relql[t] = relq[t];

  float wkr[8][8];
#pragma unroll
  for (int h = 0; h < 8; ++h) {
    const float4 a = *(const float4*)(wk + h * 512 + lane * 8);
    const float4 b = *(const float4*)(wk + h * 512 + lane * 8 + 4);
    wkr[h][0] = a.x; wkr[h][1] = a.y; wkr[h][2] = a.z; wkr[h][3] = a.w;
    wkr[h][4] = b.x; wkr[h][5] = b.y; wkr[h][6] = b.z; wkr[h][7] = b.w;
  }
  // fold-reduce leaves lane holding head myh = bitrev3(lane&7)
  const int myh = ((lane & 1) << 2) | (lane & 2) | ((lane >> 2) & 1);
  const float ck_my = ck[myh];
  const int cp = curr_pos[0];
  __syncthreads();

  float S[8][8];
#pragma unroll
  for (int h = 0; h < 8; ++h)
#pragma unroll
    for (int k = 0; k < 8; ++k) S[h][k] = 0.f;
  float s_loc = 0.f;

  const int l0 = blockIdx.x * 128 + wave * 32;
  const float* zr = zp + (size_t)l0 * 512 + lane * 8;
  float4 p0 = *(const float4*)zr;
  float4 p1 = *(const float4*)(zr + 4);

#pragma unroll 2
  for (int r = 0; r < 32; ++r) {
    const int l = l0 + r;
    // register prefetch of next row (clamped at the very end)
    const float* zn = (l + 1 < L) ? (zr + 512) : zr;
    const float4 n0 = *(const float4*)zn;
    const float4 n1 = *(const float4*)(zn + 4);
    const float zz[8] = {p0.x, p0.y, p0.z, p0.w, p1.x, p1.y, p1.z, p1.w};
    float acc[8];
#pragma unroll
    for (int h = 0; h < 8; ++h) {
      float a = 0.f;
#pragma unroll
      for (int k = 0; k < 8; ++k) a += zz[k] * wkr[h][k];
      acc[h] = a;
    }
    // fold-reduce: 8 values across 64 lanes in 10 shuffles
    const bool lo1 = (lane & 1) == 0;
    float b0 = (lo1 ? acc[0] : acc[4]) + __shfl_xor(lo1 ? acc[4] : acc[0], 1, 64);
    float b1 = (lo1 ? acc[1] : acc[5]) + __shfl_xor(lo1 ? acc[5] : acc[1], 1, 64);
    float b2 = (lo1 ? acc[2] : acc[6]) + __shfl_xor(lo1 ? acc[6] : acc[2], 1, 64);
    float b3 = (lo1 ? acc[3] : acc[7]) + __shfl_xor(lo1 ? acc[7] : acc[3], 1, 64);
    const bool lo2 = (lane & 2) == 0;
    float c0 = (lo2 ? b0 : b2) + __shfl_xor(lo2 ? b2 : b0, 2, 64);
    float c1 = (lo2 ? b1 : b3) + __shfl_xor(lo2 ? b3 : b1, 2, 64);
    const bool lo3 = (lane & 4) == 0;
    float d = (lo3 ? c0 : c1) + __shfl_xor(lo3 ? c1 : c0, 4, 64);
    d += __shfl_xor(d, 8, 64);
    d += __shfl_xor(d, 16, 64);
    d += __shfl_xor(d, 32, 64);

    int dd = cp - L + l + 64;
    dd = dd < 0 ? 0 : (dd > 128 ? 128 : dd);
    float w = __expf(d + ck_my + relql[dd * 8 + myh]);
    if (l >= L) w = 0.f;
    s_loc += w;
#pragma unroll
    for (int h = 0; h < 8; ++h) {
      const int src = ((h & 1) << 2) | (h & 2) | ((h >> 2) & 1);
      const float wh = __shfl(w, src, 64);
#pragma unroll
      for (int k = 0; k < 8; ++k) S[h][k] += wh * zz[k];
    }
    p0 = n0; p1 = n1; zr += 512;
  }

  if (lane < 8) sl[wave][myh] = s_loc;
  // merge the 4 waves' register tiles into LDS
  for (int wv = 0; wv < 4; ++wv) {
    if (wave == wv) {
#pragma unroll
      for (int h = 0; h < 8; ++h)
#pragma unroll
        for (int k = 0; k < 8; ++k) {
          const int idx = h * 512 + lane * 8 + k;
          if (wv == 0) Sl[idx] = S[h][k];
          else Sl[idx] += S[h][k];
        }
    }
    __syncthreads();
  }
  // slotted global accumulation: chain depth nb/NSLOT instead of nb
  const int slot = blockIdx.x & (NSLOT - 1);
  float* Ss = S_un + slot * 4096;
  for (int t = tid; t < 4096; t += 256) atomicAdd(&Ss[t], Sl[t]);
  if (tid < 8)
    atomicAdd(&s_out[slot * 8 + tid],
              sl[0][tid] + sl[1][tid] + sl[2][tid] + sl[3][tid]);
}

// out_real[j] = bv[j] + (sum_i Wv[j,i]*sum_sl S_un[sl,h(j),i]) / s[h(j)]. grid=128
__global__ __launch_bounds__(256) void k_outreal(
    const float* __restrict__ Wv, const float* __restrict__ S_un,
    const float* __restrict__ s, const float* __restrict__ bv,
    float* __restrict__ out_real) {
  const int wave = threadIdx.x >> 6, lane = threadIdx.x & 63;
  const int j = blockIdx.x * 4 + wave;
  const int h = j >> 6;
  const float* Mr = Wv + (size_t)j * 512 + lane * 8;
  const float4 m0 = *(const float4*)Mr;
  const float4 m1 = *(const float4*)(Mr + 4);
  float x[8] = {0.f, 0.f, 0.f, 0.f, 0.f, 0.f, 0.f, 0.f};
#pragma unroll
  for (int sl = 0; sl < NSLOT; ++sl) {
    const float* xr = S_un + sl * 4096 + h * 512 + lane * 8;
    const float4 a = *(const float4*)xr;
    const float4 b = *(const float4*)(xr + 4);
    x[0] += a.x; x[1] += a.y; x[2] += a.z; x[3] += a.w;
    x[4] += b.x; x[5] += b.y; x[6] += b.z; x[7] += b.w;
  }
  float acc = m0.x * x[0] + m0.y * x[1] + m0.z * x[2] + m0.w * x[3] +
              m1.x * x[4] + m1.y * x[5] + m1.z * x[6] + m1.w * x[7];
  acc = wave_sum(acc);
  if (lane == 0) {
    float sh = 0.f;
#pragma unroll
    for (int sl = 0; sl < NSLOT; ++sl) sh += s[sl * 8 + h];
    out_real[j] = acc / sh + bv[j];
  }
}

extern "C" void kernel_launch(void* const* d_in, const int* in_sizes, int n_in,
                              void* d_out, int out_size, void* d_ws,
                              size_t ws_size, hipStream_t stream) {
  const int* curr_pos = (const int*)d_in[0];
  const float* z_curr = (const float*)d_in[1];
  const float* z_past = (const float*)d_in[2];
  const float* Wq = (const float*)d_in[3];
  const float* bq = (const float*)d_in[4];
  const float* Wk = (const float*)d_in[5];
  const float* bk = (const float*)d_in[6];
  const float* Wv = (const float*)d_in[7];
  const float* bv = (const float*)d_in[8];
  const float* Wo = (const float*)d_in[9];
  const float* bo = (const float*)d_in[10];
  const float* rb = (const float*)d_in[11];
  float* out = (float*)d_out;

  const int L = in_sizes[2] / 512;
  const int nb = (L + 127) / 128;  // attn blocks (128 rows each)

  float* ws = (float*)d_ws;
  size_t o = 0;
  float* qp = ws + o;       o += 512;
  float* wkpart = ws + o;   o += 16 * 512;
  float* wk = ws + o;       o += 8 * 512;
  float* ck = ws + o;       o += 16;
  float* relq = ws + o;     o += 1040;
  float* s = ws + o;        o += NSLOT * 8;
  float* S_un = ws + o;     o += NSLOT * 4096;
  float* out_real = ws + o; o += 512;
  (void)ws_size; (void)n_in; (void)out_size;

  k_matvec512<<<128, 256, 0, stream>>>(Wq, z_curr, bq, qp);
  k_wkpart<<<16, 256, 0, stream>>>(Wk, qp, wkpart);
  k_misc<<<30, 256, 0, stream>>>(qp, bk, rb, wkpart, wk, ck, relq, S_un, s);
  k_attn<<<nb, 256, 0, stream>>>(z_past, wk, ck, relq, curr_pos, L, S_un, s);
  k_outreal<<<128, 256, 0, stream>>>(Wv, S_un, s, bv, out_real);
  k_matvec512<<<128, 256, 0, stream>>>(Wo, out_real, bo, out);
}

// Round 7
// 234.598 us; speedup vs baseline: 1.0932x; 1.0147x over previous
//
#include <hip/hip_runtime.h>
#include <math.h>

// MultiHeadModulator: single-query complex multi-head attention over L=65536
// past positions, dim=256 (d2=512 real), H=8 heads.
//
// Algebraic reduction (k_proj/v_proj never materialized):
//   scores[l,h] = sum_i z[l,i]*wk[h,i] + ck[h] + relq[idx(l),h]
//   S_un[h,i]   = sum_l exp(scores[l,h]) * z[l,i]     (no max-sub: scores ~N(0,0.5))
//   s[h]        = sum_l exp(scores[l,h])
//   out_real[j] = sum_i Wv[j,i]*S_un[h(j),i]/s[h(j)] + bv[j]
//   out[j']     = sum_j Wo[j',j]*out_real[j] + bo[j']
//
// v8: v7 (=238.1, slotted-atomic combine, 6 launches) minus k_misc:
//   - k_stage2 = k_wkpart blocks (0..15, byte-identical two-stage wk) +
//     relq (16..21) + ck (22) + slot-zero (23..38); all depend only on qp.
//   - k_attn prologue folds the wk-combine: reads wkpart[2h]/[2h+1] pairs,
//     (a+b)*SCALE in registers -- bit-identical arithmetic to k_misc's.
//   5 launches. NOTE: unlike v5's cursed front2 (+12us), this edit preserves
//   every compute structure; it only moves blocks between kernels.

static constexpr float SCALE = 0.17677669529663687f; // 1/sqrt(32)
static constexpr int NSLOT = 16;                     // accumulator slots

__device__ __forceinline__ float wave_sum(float v) {
#pragma unroll
  for (int off = 32; off > 0; off >>= 1) v += __shfl_xor(v, off, 64);
  return v;
}

// y[j] = bias[j] + sum_i x[i]*M[j*512+i], 512 rows, one wave per row. grid=128
__global__ __launch_bounds__(256) void k_matvec512(
    const float* __restrict__ M, const float* __restrict__ x,
    const float* __restrict__ bias, float* __restrict__ y) {
  const int wave = threadIdx.x >> 6, lane = threadIdx.x & 63;
  const int j = blockIdx.x * 4 + wave;
  const float* Mr = M + (size_t)j * 512 + lane * 8;
  const float4 m0 = *(const float4*)Mr;
  const float4 m1 = *(const float4*)(Mr + 4);
  const float4 x0 = *(const float4*)(x + lane * 8);
  const float4 x1 = *(const float4*)(x + lane * 8 + 4);
  float acc = m0.x * x0.x + m0.y * x0.y + m0.z * x0.z + m0.w * x0.w +
              m1.x * x1.x + m1.y * x1.y + m1.z * x1.z + m1.w * x1.w;
  acc = wave_sum(acc);
  if (lane == 0) y[j] = acc + bias[j];
}

// Fused stage 2 (everything that depends only on qp). grid = 39:
//  blocks 0..15 : wkpart[b,i] = sum_{j in [32b,32b+32)} qp[j]*Wk[j,i]
//                 (byte-identical to v7's k_wkpart)
//  blocks 16..21: relq[idx*8+h] = SCALE * sum_k qp[h*64+k]*rb[idx*512+h*64+k]
//  block 22     : ck[h] = SCALE * sum_k qp[h*64+k]*bk[h*64+k]
//  blocks 23..38: zero S_un slot (b-23) and s slot (b-23)
__global__ __launch_bounds__(256) void k_stage2(
    const float* __restrict__ Wk, const float* __restrict__ qp,
    const float* __restrict__ bk, const float* __restrict__ rb,
    float* __restrict__ wkpart, float* __restrict__ ck,
    float* __restrict__ relq, float* __restrict__ S_un,
    float* __restrict__ s) {
  __shared__ float ql[32];
  const int b = blockIdx.x;
  if (b < 16) {
    if (threadIdx.x < 32) ql[threadIdx.x] = qp[b * 32 + threadIdx.x];
    __syncthreads();
    for (int i = threadIdx.x; i < 512; i += 256) {
      float acc = 0.f;
#pragma unroll
      for (int k = 0; k < 32; ++k)
        acc += ql[k] * Wk[(size_t)(b * 32 + k) * 512 + i];
      wkpart[b * 512 + i] = acc;
    }
  } else if (b < 22) {
    const int t = (b - 16) * 256 + threadIdx.x;
    if (t < 129 * 8) {
      const int idx = t >> 3, h = t & 7;
      float acc = 0.f;
      for (int k = 0; k < 64; ++k)
        acc += qp[h * 64 + k] * rb[(size_t)idx * 512 + h * 64 + k];
      relq[t] = acc * SCALE;
    }
  } else if (b == 22) {
    if (threadIdx.x < 8) {
      const int h = threadIdx.x;
      float acc = 0.f;
      for (int k = 0; k < 64; ++k) acc += qp[h * 64 + k] * bk[h * 64 + k];
      ck[h] = acc * SCALE;
    }
  } else {
    const int sl = b - 23;
    for (int t = threadIdx.x; t < 4096; t += 256) S_un[sl * 4096 + t] = 0.f;
    if (threadIdx.x < 8) s[sl * 8 + threadIdx.x] = 0.f;
  }
}

// Fused single pass: scores + exp + weighted z accumulation.
// 128 rows/block (32/wave), grid = L/128 = 512 -> 2 blocks/CU.
// Prologue folds the wk-combine from wkpart (bit-identical arithmetic).
// Tail: 4-wave LDS merge, then atomicAdd into slot (blockIdx & 15) of S_un/s.
__global__ __launch_bounds__(256, 2) void k_attn(
    const float* __restrict__ zp, const float* __restrict__ wkpart,
    const float* __restrict__ ck, const float* __restrict__ relq,
    const int* __restrict__ curr_pos, int L, float* __restrict__ S_un,
    float* __restrict__ s_out) {
  __shared__ float relql[1032];
  __shared__ float Sl[4096];
  __shared__ float sl[4][8];
  const int tid = threadIdx.x;
  const int wave = tid >> 6, lane = tid & 63;
  for (int t = tid; t < 1032; t += 256) relql[t] = relq[t];

  float wkr[8][8];
#pragma unroll
  for (int h = 0; h < 8; ++h) {
    const float4 a0 = *(const float4*)(wkpart + (2 * h) * 512 + lane * 8);
    const float4 a1 = *(const float4*)(wkpart + (2 * h) * 512 + lane * 8 + 4);
    const float4 b0 = *(const float4*)(wkpart + (2 * h + 1) * 512 + lane * 8);
    const float4 b1 = *(const float4*)(wkpart + (2 * h + 1) * 512 + lane * 8 + 4);
    wkr[h][0] = (a0.x + b0.x) * SCALE; wkr[h][1] = (a0.y + b0.y) * SCALE;
    wkr[h][2] = (a0.z + b0.z) * SCALE; wkr[h][3] = (a0.w + b0.w) * SCALE;
    wkr[h][4] = (a1.x + b1.x) * SCALE; wkr[h][5] = (a1.y + b1.y) * SCALE;
    wkr[h][6] = (a1.z + b1.z) * SCALE; wkr[h][7] = (a1.w + b1.w) * SCALE;
  }
  // fold-reduce leaves lane holding head myh = bitrev3(lane&7)
  const int myh = ((lane & 1) << 2) | (lane & 2) | ((lane >> 2) & 1);
  const float ck_my = ck[myh];
  const int cp = curr_pos[0];
  __syncthreads();

  float S[8][8];
#pragma unroll
  for (int h = 0; h < 8; ++h)
#pragma unroll
    for (int k = 0; k < 8; ++k) S[h][k] = 0.f;
  float s_loc = 0.f;

  const int l0 = blockIdx.x * 128 + wave * 32;
  const float* zr = zp + (size_t)l0 * 512 + lane * 8;
  float4 p0 = *(const float4*)zr;
  float4 p1 = *(const float4*)(zr + 4);

#pragma unroll 2
  for (int r = 0; r < 32; ++r) {
    const int l = l0 + r;
    // register prefetch of next row (clamped at the very end)
    const float* zn = (l + 1 < L) ? (zr + 512) : zr;
    const float4 n0 = *(const float4*)zn;
    const float4 n1 = *(const float4*)(zn + 4);
    const float zz[8] = {p0.x, p0.y, p0.z, p0.w, p1.x, p1.y, p1.z, p1.w};
    float acc[8];
#pragma unroll
    for (int h = 0; h < 8; ++h) {
      float a = 0.f;
#pragma unroll
      for (int k = 0; k < 8; ++k) a += zz[k] * wkr[h][k];
      acc[h] = a;
    }
    // fold-reduce: 8 values across 64 lanes in 10 shuffles
    const bool lo1 = (lane & 1) == 0;
    float b0 = (lo1 ? acc[0] : acc[4]) + __shfl_xor(lo1 ? acc[4] : acc[0], 1, 64);
    float b1 = (lo1 ? acc[1] : acc[5]) + __shfl_xor(lo1 ? acc[5] : acc[1], 1, 64);
    float b2 = (lo1 ? acc[2] : acc[6]) + __shfl_xor(lo1 ? acc[6] : acc[2], 1, 64);
    float b3 = (lo1 ? acc[3] : acc[7]) + __shfl_xor(lo1 ? acc[7] : acc[3], 1, 64);
    const bool lo2 = (lane & 2) == 0;
    float c0 = (lo2 ? b0 : b2) + __shfl_xor(lo2 ? b2 : b0, 2, 64);
    float c1 = (lo2 ? b1 : b3) + __shfl_xor(lo2 ? b3 : b1, 2, 64);
    const bool lo3 = (lane & 4) == 0;
    float d = (lo3 ? c0 : c1) + __shfl_xor(lo3 ? c1 : c0, 4, 64);
    d += __shfl_xor(d, 8, 64);
    d += __shfl_xor(d, 16, 64);
    d += __shfl_xor(d, 32, 64);

    int dd = cp - L + l + 64;
    dd = dd < 0 ? 0 : (dd > 128 ? 128 : dd);
    float w = __expf(d + ck_my + relql[dd * 8 + myh]);
    if (l >= L) w = 0.f;
    s_loc += w;
#pragma unroll
    for (int h = 0; h < 8; ++h) {
      const int src = ((h & 1) << 2) | (h & 2) | ((h >> 2) & 1);
      const float wh = __shfl(w, src, 64);
#pragma unroll
      for (int k = 0; k < 8; ++k) S[h][k] += wh * zz[k];
    }
    p0 = n0; p1 = n1; zr += 512;
  }

  if (lane < 8) sl[wave][myh] = s_loc;
  // merge the 4 waves' register tiles into LDS
  for (int wv = 0; wv < 4; ++wv) {
    if (wave == wv) {
#pragma unroll
      for (int h = 0; h < 8; ++h)
#pragma unroll
        for (int k = 0; k < 8; ++k) {
          const int idx = h * 512 + lane * 8 + k;
          if (wv == 0) Sl[idx] = S[h][k];
          else Sl[idx] += S[h][k];
        }
    }
    __syncthreads();
  }
  // slotted global accumulation: chain depth nb/NSLOT instead of nb
  const int slot = blockIdx.x & (NSLOT - 1);
  float* Ss = S_un + slot * 4096;
  for (int t = tid; t < 4096; t += 256) atomicAdd(&Ss[t], Sl[t]);
  if (tid < 8)
    atomicAdd(&s_out[slot * 8 + tid],
              sl[0][tid] + sl[1][tid] + sl[2][tid] + sl[3][tid]);
}

// out_real[j] = bv[j] + (sum_i Wv[j,i]*sum_sl S_un[sl,h(j),i]) / s[h(j)]. grid=128
__global__ __launch_bounds__(256) void k_outreal(
    const float* __restrict__ Wv, const float* __restrict__ S_un,
    const float* __restrict__ s, const float* __restrict__ bv,
    float* __restrict__ out_real) {
  const int wave = threadIdx.x >> 6, lane = threadIdx.x & 63;
  const int j = blockIdx.x * 4 + wave;
  const int h = j >> 6;
  const float* Mr = Wv + (size_t)j * 512 + lane * 8;
  const float4 m0 = *(const float4*)Mr;
  const float4 m1 = *(const float4*)(Mr + 4);
  float x[8] = {0.f, 0.f, 0.f, 0.f, 0.f, 0.f, 0.f, 0.f};
#pragma unroll
  for (int sl = 0; sl < NSLOT; ++sl) {
    const float* xr = S_un + sl * 4096 + h * 512 + lane * 8;
    const float4 a = *(const float4*)xr;
    const float4 b = *(const float4*)(xr + 4);
    x[0] += a.x; x[1] += a.y; x[2] += a.z; x[3] += a.w;
    x[4] += b.x; x[5] += b.y; x[6] += b.z; x[7] += b.w;
  }
  float acc = m0.x * x[0] + m0.y * x[1] + m0.z * x[2] + m0.w * x[3] +
              m1.x * x[4] + m1.y * x[5] + m1.z * x[6] + m1.w * x[7];
  acc = wave_sum(acc);
  if (lane == 0) {
    float sh = 0.f;
#pragma unroll
    for (int sl = 0; sl < NSLOT; ++sl) sh += s[sl * 8 + h];
    out_real[j] = acc / sh + bv[j];
  }
}

extern "C" void kernel_launch(void* const* d_in, const int* in_sizes, int n_in,
                              void* d_out, int out_size, void* d_ws,
                              size_t ws_size, hipStream_t stream) {
  const int* curr_pos = (const int*)d_in[0];
  const float* z_curr = (const float*)d_in[1];
  const float* z_past = (const float*)d_in[2];
  const float* Wq = (const float*)d_in[3];
  const float* bq = (const float*)d_in[4];
  const float* Wk = (const float*)d_in[5];
  const float* bk = (const float*)d_in[6];
  const float* Wv = (const float*)d_in[7];
  const float* bv = (const float*)d_in[8];
  const float* Wo = (const float*)d_in[9];
  const float* bo = (const float*)d_in[10];
  const float* rb = (const float*)d_in[11];
  float* out = (float*)d_out;

  const int L = in_sizes[2] / 512;
  const int nb = (L + 127) / 128;  // attn blocks (128 rows each)

  float* ws = (float*)d_ws;
  size_t o = 0;
  float* qp = ws + o;       o += 512;
  float* wkpart = ws + o;   o += 16 * 512;
  float* ck = ws + o;       o += 16;
  float* relq = ws + o;     o += 1040;
  float* s = ws + o;        o += NSLOT * 8;
  float* S_un = ws + o;     o += NSLOT * 4096;
  float* out_real = ws + o; o += 512;
  (void)ws_size; (void)n_in; (void)out_size;

  k_matvec512<<<128, 256, 0, stream>>>(Wq, z_curr, bq, qp);
  k_stage2<<<39, 256, 0, stream>>>(Wk, qp, bk, rb, wkpart, ck, relq, S_un, s);
  k_attn<<<nb, 256, 0, stream>>>(z_past, wkpart, ck, relq, curr_pos, L, S_un, s);
  k_outreal<<<128, 256, 0, stream>>>(Wv, S_un, s, bv, out_real);
  k_matvec512<<<128, 256, 0, stream>>>(Wo, out_real, bo, out);
}